// Round 1
// baseline (3642.241 us; speedup 1.0000x reference)
//
#include <hip/hip_runtime.h>
#include <math.h>

constexpr int V_ = 50000, D_ = 128, B_ = 1024, P_ = 50;
constexpr int N_ = 51200, E_ = 51200;
constexpr long long NS_ = (long long)N_ * D_;
constexpr float SCALE_ = 12.0f;

static __device__ __forceinline__ float wsum(float v) {
    #pragma unroll
    for (int o = 32; o; o >>= 1) v += __shfl_xor(v, o, 64);
    return v;
}
static __device__ __forceinline__ float wmax(float v) {
    #pragma unroll
    for (int o = 32; o; o >>= 1) v = fmaxf(v, __shfl_xor(v, o, 64));
    return v;
}
static __device__ __forceinline__ float sig(float x) { return 1.f / (1.f + expf(-x)); }

// ---------------- dt = max(edge_t) ----------------
__global__ void k_dtmax(const float* __restrict__ et, float* __restrict__ dt) {
    __shared__ float s[256];
    float m = 0.f;
    for (int i = threadIdx.x; i < E_; i += 256) m = fmaxf(m, et[i]);
    s[threadIdx.x] = m; __syncthreads();
    for (int o = 128; o; o >>= 1) {
        if (threadIdx.x < o) s[threadIdx.x] = fmaxf(s[threadIdx.x], s[threadIdx.x + o]);
        __syncthreads();
    }
    if (threadIdx.x == 0) *dt = s[0];
}

// ---------------- feat = normalize(embedding[iid]) ----------------
__global__ void k_feat0(const float* __restrict__ emb, const int* __restrict__ iid,
                        float* __restrict__ feat) {
    int row = blockIdx.x * 4 + (threadIdx.x >> 6);
    int l = threadIdx.x & 63;
    const float* p = emb + (long long)iid[row] * D_;
    float a = p[l], b = p[l + 64];
    float ss = wsum(a * a + b * b);
    float s = 1.f / (sqrtf(ss) + 1e-12f);
    float* q = feat + (long long)row * D_;
    q[l] = a * s; q[l + 64] = b * s;
}

// ---------------- stage-A edge aggregation ----------------
__global__ void k_aggA(const int* __restrict__ esrc, const int* __restrict__ edst,
                       const float* __restrict__ ew, const float* __restrict__ feat,
                       float* __restrict__ m_in, float* __restrict__ m_out,
                       float* __restrict__ ws_in, float* __restrict__ ws_out) {
    int e = blockIdx.x * 2 + (threadIdx.x >> 7);
    int d = threadIdx.x & 127;
    int s_ = esrc[e], d_ = edst[e];
    float w = ew[e];
    atomicAdd(&m_in[(long long)d_ * D_ + d], feat[(long long)s_ * D_ + d] * w);
    atomicAdd(&m_out[(long long)s_ * D_ + d], feat[(long long)d_ * D_ + d] * w);
    if (d == 0) { atomicAdd(&ws_in[d_], w); atomicAdd(&ws_out[s_], w); }
}

__global__ void k_div(float* __restrict__ m, const float* __restrict__ ws) {
    long long i = (long long)blockIdx.x * 256 + threadIdx.x;
    if (i >= NS_) return;
    float w = ws[i >> 7];
    m[i] = m[i] / (w > 0.f ? w : 1.f);
}

// M[k][j] = sum_{c<256} W[k][c] * wih[j][coff+c]
__global__ void k_prec(const float* __restrict__ W, const float* __restrict__ wih, int coff,
                       float* __restrict__ M) {
    int idx = blockIdx.x * 256 + threadIdx.x;
    if (idx >= 128 * 384) return;
    int k = idx / 384, j = idx % 384;
    const float* wr = W + (long long)k * 256;
    const float* ir = wih + (long long)j * 512 + coff;
    float s = 0.f;
    for (int c = 0; c < 256; c++) s += wr[c] * ir[c];
    M[(long long)k * 384 + j] = s;
}

// ---------------- generic tiled GEMM, K=128 fixed ----------------
// C[i][j] = act( (rs1[i]*A1[i]) @ B1 [+ (rs2[i]*A2[i]) @ B2] + bias1 + bias2 ) * cscale * outmul
// BT: B stored as [col][k] (row-major, ld 128). else B row-major [k][ldb].
template<int DUAL, int BT, int ACT>
__launch_bounds__(256, 2)
__global__ void k_gemm(const float* __restrict__ A1, const float* __restrict__ rs1,
                       const float* __restrict__ B1,
                       const float* __restrict__ A2, const float* __restrict__ rs2,
                       const float* __restrict__ B2, int ldb,
                       const float* __restrict__ bias1, const float* __restrict__ bias2,
                       const float* __restrict__ cscale, float outmul,
                       float* __restrict__ C, int ncols, int ldc) {
    __shared__ float As1[32][68], Bs1[32][68];
    __shared__ float As2[32][68], Bs2[32][68];
    const int t = threadIdx.x;
    const int bx = blockIdx.x, by = blockIdx.y;
    const int tx = t & 15, ty = t >> 4;
    float acc[4][4] = {};
    for (int ks = 0; ks < 128; ks += 32) {
        #pragma unroll
        for (int i = 0; i < 8; i++) {
            int idx = t + i * 256;
            int k = idx & 31, m = idx >> 5;
            long long row = (long long)by * 64 + m;
            float s1 = rs1 ? rs1[row] : 1.f;
            As1[k][m] = A1[row * 128 + ks + k] * s1;
            if (DUAL) {
                float s2 = rs2 ? rs2[row] : 1.f;
                As2[k][m] = A2[row * 128 + ks + k] * s2;
            }
        }
        #pragma unroll
        for (int i = 0; i < 8; i++) {
            int idx = t + i * 256;
            int k, n;
            if (BT) { k = idx & 31; n = idx >> 5; }
            else    { n = idx & 63; k = idx >> 6; }
            int col = bx * 64 + n;
            float v1 = 0.f, v2 = 0.f;
            if (col < ncols) {
                if (BT) {
                    v1 = B1[(long long)col * 128 + ks + k];
                    if (DUAL) v2 = B2[(long long)col * 128 + ks + k];
                } else {
                    v1 = B1[(long long)(ks + k) * ldb + col];
                    if (DUAL) v2 = B2[(long long)(ks + k) * ldb + col];
                }
            }
            Bs1[k][n] = v1;
            if (DUAL) Bs2[k][n] = v2;
        }
        __syncthreads();
        #pragma unroll
        for (int k = 0; k < 32; k++) {
            float4 a1 = *(const float4*)&As1[k][ty * 4];
            float4 b1 = *(const float4*)&Bs1[k][tx * 4];
            float av[4] = {a1.x, a1.y, a1.z, a1.w};
            float bv[4] = {b1.x, b1.y, b1.z, b1.w};
            float av2[4], bv2[4];
            if (DUAL) {
                float4 a2 = *(const float4*)&As2[k][ty * 4];
                float4 b2 = *(const float4*)&Bs2[k][tx * 4];
                av2[0] = a2.x; av2[1] = a2.y; av2[2] = a2.z; av2[3] = a2.w;
                bv2[0] = b2.x; bv2[1] = b2.y; bv2[2] = b2.z; bv2[3] = b2.w;
            }
            #pragma unroll
            for (int i = 0; i < 4; i++)
                #pragma unroll
                for (int j = 0; j < 4; j++) {
                    acc[i][j] += av[i] * bv[j];
                    if (DUAL) acc[i][j] += av2[i] * bv2[j];
                }
        }
        __syncthreads();
    }
    #pragma unroll
    for (int i = 0; i < 4; i++) {
        long long row = (long long)by * 64 + ty * 4 + i;
        #pragma unroll
        for (int j = 0; j < 4; j++) {
            int col = bx * 64 + tx * 4 + j;
            if (col < ncols) {
                float v = acc[i][j];
                if (bias1) v += bias1[col];
                if (bias2) v += bias2[col];
                if (cscale) v *= cscale[col];
                v *= outmul;
                if (ACT == 1) v = sig(v);
                else if (ACT == 2) v = tanhf(v);
                C[row * ldc + col] = v;
            }
        }
    }
}

// ---------------- GRU + renorm ----------------
__global__ void k_gru(const float* __restrict__ gi, const float* __restrict__ gh,
                      float* __restrict__ feat) {
    int row = blockIdx.x * 4 + (threadIdx.x >> 6);
    int l = threadIdx.x & 63;
    const float* gir = gi + (long long)row * 384;
    const float* ghr = gh + (long long)row * 384;
    float* fr = feat + (long long)row * 128;
    float nv[2]; float ss = 0.f;
    #pragma unroll
    for (int tq = 0; tq < 2; tq++) {
        int d = l + tq * 64;
        float ir = gir[d], iz = gir[128 + d], in_ = gir[256 + d];
        float hr = ghr[d], hz = ghr[128 + d], hn = ghr[256 + d];
        float r = sig(ir + hr);
        float z = sig(iz + hz);
        float n = tanhf(in_ + r * hn);
        float fv = fr[d];
        nv[tq] = (1.f - z) * n + z * fv;
        ss += nv[tq] * nv[tq];
    }
    ss = wsum(ss);
    float s = 1.f / fmaxf(sqrtf(ss), 1e-12f);
    fr[l] = nv[0] * s; fr[l + 64] = nv[1] * s;
}

// ---------------- GCN mask/deg/agg ----------------
__global__ void k_deg(const int* __restrict__ esrc, const int* __restrict__ edst,
                      const float* __restrict__ et, const float* __restrict__ dtp,
                      float tfac, float* __restrict__ deg) {
    int e = blockIdx.x * 256 + threadIdx.x;
    if (e >= E_) return;
    int s = esrc[e], d = edst[e];
    float tv = tfac * (*dtp);
    if (s != d && et[e] <= tv) { atomicAdd(&deg[s], 1.f); atomicAdd(&deg[d], 1.f); }
}

__global__ void k_nrm(const float* __restrict__ deg, float* __restrict__ nrm) {
    int i = blockIdx.x * 256 + threadIdx.x;
    if (i >= N_) return;
    nrm[i] = 1.f / sqrtf(fmaxf(deg[i], 1.f));
}

__global__ void k_gagg(const int* __restrict__ esrc, const int* __restrict__ edst,
                       const float* __restrict__ et, const float* __restrict__ dtp,
                       float tfac, const float* __restrict__ v,
                       const float* __restrict__ nrm, float* __restrict__ agg) {
    int e = blockIdx.x * 2 + (threadIdx.x >> 7);
    int d = threadIdx.x & 127;
    int s = esrc[e], dd = edst[e];
    if (s == dd) return;
    float tv = tfac * (*dtp);
    if (et[e] > tv) return;
    atomicAdd(&agg[(long long)dd * D_ + d], v[(long long)s * D_ + d] * nrm[s]);
    atomicAdd(&agg[(long long)s * D_ + d], v[(long long)dd * D_ + d] * nrm[dd]);
}

__global__ void k_mul(float* __restrict__ a, const float* __restrict__ b) {
    long long i = (long long)blockIdx.x * 256 + threadIdx.x;
    if (i >= NS_) return;
    a[i] *= b[i];
}

// dh = normalize_maxeps((1-z)*(u-h))
__global__ void k_dh(const float* __restrict__ z, const float* __restrict__ u,
                     const float* __restrict__ h, float* __restrict__ out) {
    int row = blockIdx.x * 4 + (threadIdx.x >> 6);
    int l = threadIdx.x & 63;
    long long base = (long long)row * 128;
    float v[2]; float ss = 0.f;
    #pragma unroll
    for (int tq = 0; tq < 2; tq++) {
        int d = l + tq * 64;
        float zz = z[base + d], uu = u[base + d], hh = h[base + d];
        v[tq] = (1.f - zz) * (uu - hh);
        ss += v[tq] * v[tq];
    }
    ss = wsum(ss);
    float s = 1.f / fmaxf(sqrtf(ss), 1e-12f);
    out[base + l] = v[0] * s; out[base + l + 64] = v[1] * s;
}

__global__ void k_update(const float* __restrict__ k, const float* __restrict__ feat,
                         float* __restrict__ acc, float* __restrict__ h,
                         const float* __restrict__ dtp, float accw, float hfac, int first) {
    long long i = (long long)blockIdx.x * 256 + threadIdx.x;
    if (i >= NS_) return;
    float kv = k[i];
    float a = first ? accw * kv : acc[i] + accw * kv;
    acc[i] = a;
    if (hfac != 0.f) h[i] = feat[i] + hfac * (*dtp) * kv;
}

__global__ void k_fin(float* __restrict__ feat, const float* __restrict__ acc,
                      const float* __restrict__ dtp) {
    int row = blockIdx.x * 4 + (threadIdx.x >> 6);
    int l = threadIdx.x & 63;
    long long base = (long long)row * 128;
    float dt6 = (*dtp) / 6.f;
    float v0 = feat[base + l] + dt6 * acc[base + l];
    float v1 = feat[base + l + 64] + dt6 * acc[base + l + 64];
    float ss = wsum(v0 * v0 + v1 * v1);
    float s = 1.f / sqrtf(ss);
    feat[base + l] = v0 * s; feat[base + l + 64] = v1 * s;
}

// ---------------- readout ----------------
__global__ void k_fv(const float* __restrict__ feat, const int* __restrict__ last,
                     const float* __restrict__ Wv, const float* __restrict__ bv,
                     float* __restrict__ fv) {
    __shared__ float fr[128];
    int b = blockIdx.x; int j = threadIdx.x;
    fr[j] = feat[(long long)last[b] * 128 + j];
    __syncthreads();
    float s = bv[j];
    for (int k = 0; k < 128; k++) s += fr[k] * Wv[(long long)k * 128 + j];
    fv[(long long)b * 128 + j] = s;
}

__global__ void k_e(const float* __restrict__ fu, const float* __restrict__ fv,
                    const int* __restrict__ gid, const float* __restrict__ fce,
                    float* __restrict__ e) {
    int row = blockIdx.x * 4 + (threadIdx.x >> 6);
    int l = threadIdx.x & 63;
    int g = gid[row];
    float s = 0.f;
    #pragma unroll
    for (int tq = 0; tq < 2; tq++) {
        int d = l + tq * 64;
        float x = fu[(long long)row * 128 + d] + fv[(long long)g * 128 + d];
        s += sig(x) * fce[d];
    }
    s = wsum(s);
    if (l == 0) e[row] = s;
}

__global__ void k_softg(const float* __restrict__ e, float* __restrict__ alpha) {
    int b = blockIdx.x; int l = threadIdx.x;
    float v = (l < P_) ? e[b * P_ + l] : -1e30f;
    float m = wmax(v);
    float ex = (l < P_) ? expf(v - m) : 0.f;
    float s = wsum(ex);
    if (l < P_) alpha[b * P_ + l] = ex / s;
}

__global__ void k_srg(const float* __restrict__ feat, const float* __restrict__ alpha,
                      float* __restrict__ srg) {
    int b = blockIdx.x; int d = threadIdx.x;
    float s = 0.f;
    for (int p = 0; p < P_; p++)
        s += feat[(long long)(b * P_ + p) * 128 + d] * alpha[b * P_ + p];
    srg[(long long)b * 128 + d] = s;
}

__global__ void k_sr(const float* __restrict__ feat, const int* __restrict__ last,
                     const float* __restrict__ srg, const float* __restrict__ Wsr,
                     float* __restrict__ sr) {
    __shared__ float in[256];
    __shared__ float red[2];
    int b = blockIdx.x; int j = threadIdx.x;
    in[j] = feat[(long long)last[b] * 128 + j];
    in[128 + j] = srg[(long long)b * 128 + j];
    __syncthreads();
    float s = 0.f;
    for (int k = 0; k < 256; k++) s += in[k] * Wsr[(long long)k * 128 + j];
    float ss = wsum(s * s);
    if ((j & 63) == 0) red[j >> 6] = ss;
    __syncthreads();
    float nrm = sqrtf(red[0] + red[1]);
    sr[(long long)b * 128 + j] = s / (nrm + 1e-12f);
}

__global__ void k_rn(const float* __restrict__ emb, float* __restrict__ rn) {
    int row = blockIdx.x * 4 + (threadIdx.x >> 6);
    if (row >= V_) return;
    int l = threadIdx.x & 63;
    const float* p = emb + (long long)row * 128;
    float a = p[l], b = p[l + 64];
    float ss = wsum(a * a + b * b);
    if (l == 0) rn[row] = 1.f / (sqrtf(ss) + 1e-12f);
}

__global__ void k_lsm(float* __restrict__ out) {
    __shared__ float sm[256], ssum[256];
    int b = blockIdx.x;
    float* row = out + (long long)b * V_;
    float m = -1e30f, s = 0.f;
    for (int i = threadIdx.x; i < V_; i += 256) {
        float v = row[i];
        if (v > m) { s = s * expf(m - v) + 1.f; m = v; }
        else s += expf(v - m);
    }
    sm[threadIdx.x] = m; ssum[threadIdx.x] = s; __syncthreads();
    for (int o = 128; o; o >>= 1) {
        if (threadIdx.x < o) {
            float m1 = sm[threadIdx.x], s1 = ssum[threadIdx.x];
            float m2 = sm[threadIdx.x + o], s2 = ssum[threadIdx.x + o];
            float mm = fmaxf(m1, m2);
            sm[threadIdx.x] = mm;
            ssum[threadIdx.x] = s1 * expf(m1 - mm) + s2 * expf(m2 - mm);
        }
        __syncthreads();
    }
    float M = sm[0], L = logf(ssum[0]);
    for (int i = threadIdx.x; i < V_; i += 256) row[i] = row[i] - M - L;
}

// ================= host orchestration =================
extern "C" void kernel_launch(void* const* d_in, const int* in_sizes, int n_in,
                              void* d_out, int out_size, void* d_ws, size_t ws_size,
                              hipStream_t stream) {
    const int* iid   = (const int*)d_in[0];
    const int* esrc  = (const int*)d_in[1];
    const int* edst  = (const int*)d_in[2];
    const int* gid   = (const int*)d_in[3];
    const int* last  = (const int*)d_in[4];
    const float* ew  = (const float*)d_in[5];
    const float* et  = (const float*)d_in[6];
    const float* emb = (const float*)d_in[7];
    const float* W1  = (const float*)d_in[8];
    const float* W2  = (const float*)d_in[9];
    const float* wih = (const float*)d_in[10];
    const float* whh = (const float*)d_in[11];
    const float* bih = (const float*)d_in[12];
    const float* bhh = (const float*)d_in[13];
    const float* Wxr = (const float*)d_in[14]; const float* bxr = (const float*)d_in[15];
    const float* Wxz = (const float*)d_in[16]; const float* bxz = (const float*)d_in[17];
    const float* Wxh = (const float*)d_in[18]; const float* bxh = (const float*)d_in[19];
    const float* Whr = (const float*)d_in[20]; const float* bhr = (const float*)d_in[21];
    const float* Whz = (const float*)d_in[22]; const float* bhz = (const float*)d_in[23];
    const float* Whh = (const float*)d_in[24]; const float* bhh2 = (const float*)d_in[25];
    const float* fcu = (const float*)d_in[26];
    const float* fvw = (const float*)d_in[27]; const float* fvbv = (const float*)d_in[28];
    const float* fce = (const float*)d_in[29];
    const float* fsr = (const float*)d_in[30];
    float* out = (float*)d_out;

    float* Wk = (float*)d_ws;
    auto S = [&](int i) { return Wk + (long long)i * NS_; };
    float* FEAT = S(0);
    float* MIN = S(1);  float* H   = S(1);
    float* MOUT = S(2); float* ACC = S(2);
    float* GI = S(3);   float* KBUF = S(3); float* FU = S(3);
    float* AX = S(4);
    float* AH = S(5);
    float* GH = S(6);   float* RB = S(6);
    float* ZB = S(7);
    float* small = Wk + 9 * NS_;
    float* ws_in = small;  small += N_;
    float* ws_out = small; small += N_;
    float* deg = small;    small += N_;
    float* nrm = small;    small += N_;
    float* evec = small;   small += N_;
    float* alpha = small;  small += N_;
    float* dtp = small;    small += 64;
    float* M1 = small;     small += 128 * 384;
    float* M2 = small;     small += 128 * 384;
    float* fvb = small;    small += B_ * 128;
    float* srg = small;    small += B_ * 128;
    float* srb = small;    small += B_ * 128;
    float* rnv = small;    small += V_;

    k_dtmax<<<1, 256, 0, stream>>>(et, dtp);
    k_feat0<<<N_ / 4, 256, 0, stream>>>(emb, iid, FEAT);

    // ---- stage A: weighted neighbor agg + GRU ----
    hipMemsetAsync(MIN, 0, NS_ * 4, stream);
    hipMemsetAsync(MOUT, 0, NS_ * 4, stream);
    hipMemsetAsync(ws_in, 0, N_ * 4, stream);
    hipMemsetAsync(ws_out, 0, N_ * 4, stream);
    k_aggA<<<E_ / 2, 256, 0, stream>>>(esrc, edst, ew, FEAT, MIN, MOUT, ws_in, ws_out);
    k_div<<<(int)(NS_ / 256), 256, 0, stream>>>(MIN, ws_in);
    k_div<<<(int)(NS_ / 256), 256, 0, stream>>>(MOUT, ws_out);
    k_prec<<<192, 256, 0, stream>>>(W1, wih, 0, M1);
    k_prec<<<192, 256, 0, stream>>>(W2, wih, 256, M2);
    k_gemm<1, 0, 0><<<dim3(6, N_ / 64), 256, 0, stream>>>(
        MIN, nullptr, M1, MOUT, nullptr, M2, 384, bih, nullptr, nullptr, 1.f, GI, 384, 384);
    k_gemm<0, 1, 0><<<dim3(6, N_ / 64), 256, 0, stream>>>(
        FEAT, nullptr, whh, nullptr, nullptr, nullptr, 128, bhh, nullptr, nullptr, 1.f, GH, 384, 384);
    k_gru<<<N_ / 4, 256, 0, stream>>>(GI, GH, FEAT);

    // ---- stage B: RK4 ODE ----
    hipMemcpyAsync(H, FEAT, NS_ * 4, hipMemcpyDeviceToDevice, stream);

    auto fstep = [&](float tfac, bool newmask, bool hx_same) {
        if (newmask) {
            hipMemsetAsync(deg, 0, N_ * 4, stream);
            k_deg<<<E_ / 256, 256, 0, stream>>>(esrc, edst, et, dtp, tfac, deg);
            k_nrm<<<N_ / 256, 256, 0, stream>>>(deg, nrm);
            hipMemsetAsync(AX, 0, NS_ * 4, stream);
            k_gagg<<<E_ / 2, 256, 0, stream>>>(esrc, edst, et, dtp, tfac, FEAT, nrm, AX);
        }
        const float* AHp = AX;
        if (!hx_same) {
            hipMemsetAsync(AH, 0, NS_ * 4, stream);
            k_gagg<<<E_ / 2, 256, 0, stream>>>(esrc, edst, et, dtp, tfac, H, nrm, AH);
            AHp = AH;
        }
        k_gemm<1, 0, 1><<<dim3(2, N_ / 64), 256, 0, stream>>>(
            AX, nrm, Wxr, AHp, nrm, Whr, 128, bxr, bhr, nullptr, 1.f, RB, 128, 128);
        k_gemm<1, 0, 1><<<dim3(2, N_ / 64), 256, 0, stream>>>(
            AX, nrm, Wxz, AHp, nrm, Whz, 128, bxz, bhz, nullptr, 1.f, ZB, 128, 128);
        k_mul<<<(int)(NS_ / 256), 256, 0, stream>>>(RB, H);
        hipMemsetAsync(AH, 0, NS_ * 4, stream);
        k_gagg<<<E_ / 2, 256, 0, stream>>>(esrc, edst, et, dtp, tfac, RB, nrm, AH);
        k_gemm<1, 0, 2><<<dim3(2, N_ / 64), 256, 0, stream>>>(
            AX, nrm, Wxh, AH, nrm, Whh, 128, bxh, bhh2, nullptr, 1.f, RB, 128, 128);
        k_dh<<<N_ / 4, 256, 0, stream>>>(ZB, RB, H, KBUF);
    };

    fstep(0.0f, true, true);
    k_update<<<(int)(NS_ / 256), 256, 0, stream>>>(KBUF, FEAT, ACC, H, dtp, 1.f, 0.5f, 1);
    fstep(0.5f, true, false);
    k_update<<<(int)(NS_ / 256), 256, 0, stream>>>(KBUF, FEAT, ACC, H, dtp, 2.f, 0.5f, 0);
    fstep(0.5f, false, false);
    k_update<<<(int)(NS_ / 256), 256, 0, stream>>>(KBUF, FEAT, ACC, H, dtp, 2.f, 1.0f, 0);
    fstep(1.0f, true, false);
    k_update<<<(int)(NS_ / 256), 256, 0, stream>>>(KBUF, FEAT, ACC, H, dtp, 1.f, 0.0f, 0);
    k_fin<<<N_ / 4, 256, 0, stream>>>(FEAT, ACC, dtp);

    // ---- readout ----
    k_gemm<0, 0, 0><<<dim3(2, N_ / 64), 256, 0, stream>>>(
        FEAT, nullptr, fcu, nullptr, nullptr, nullptr, 128, nullptr, nullptr, nullptr, 1.f, FU, 128, 128);
    k_fv<<<B_, 128, 0, stream>>>(FEAT, last, fvw, fvbv, fvb);
    k_e<<<N_ / 4, 256, 0, stream>>>(FU, fvb, gid, fce, evec);
    k_softg<<<B_, 64, 0, stream>>>(evec, alpha);
    k_srg<<<B_, 128, 0, stream>>>(FEAT, alpha, srg);
    k_sr<<<B_, 128, 0, stream>>>(FEAT, last, srg, fsr, srb);
    k_rn<<<(V_ + 3) / 4, 256, 0, stream>>>(emb, rnv);
    k_gemm<0, 1, 0><<<dim3((V_ + 63) / 64, B_ / 64), 256, 0, stream>>>(
        srb, nullptr, emb, nullptr, nullptr, nullptr, 128, nullptr, nullptr, rnv, SCALE_,
        out, V_, V_);
    k_lsm<<<B_, 256, 0, stream>>>(out);
}

// Round 3
// 1513.961 us; speedup vs baseline: 2.4058x; 2.4058x over previous
//
#include <hip/hip_runtime.h>
#include <math.h>

constexpr int V_ = 50000, D_ = 128, B_ = 1024, P_ = 50;
constexpr int N_ = 51200, E_ = 51200;
constexpr long long NS_ = (long long)N_ * D_;
constexpr float SCALE_ = 12.0f;

typedef __attribute__((ext_vector_type(8))) unsigned short u16x8;
typedef __attribute__((ext_vector_type(8))) __bf16 bf16x8;
typedef __attribute__((ext_vector_type(4))) float f32x4;

static __device__ __forceinline__ float wsum(float v) {
    #pragma unroll
    for (int o = 32; o; o >>= 1) v += __shfl_xor(v, o, 64);
    return v;
}
static __device__ __forceinline__ float wmax(float v) {
    #pragma unroll
    for (int o = 32; o; o >>= 1) v = fmaxf(v, __shfl_xor(v, o, 64));
    return v;
}
static __device__ __forceinline__ float sig(float x) { return 1.f / (1.f + expf(-x)); }

// fp32 -> bf16 round-to-nearest-even
static __device__ __forceinline__ unsigned short f2b(float x) {
    unsigned u = __float_as_uint(x);
    u += 0x7fffu + ((u >> 16) & 1u);
    return (unsigned short)(u >> 16);
}

// ---------------- dt = max(edge_t) ----------------
__global__ void k_dtmax(const float* __restrict__ et, float* __restrict__ dt) {
    __shared__ float s[256];
    float m = 0.f;
    for (int i = threadIdx.x; i < E_; i += 256) m = fmaxf(m, et[i]);
    s[threadIdx.x] = m; __syncthreads();
    for (int o = 128; o; o >>= 1) {
        if (threadIdx.x < o) s[threadIdx.x] = fmaxf(s[threadIdx.x], s[threadIdx.x + o]);
        __syncthreads();
    }
    if (threadIdx.x == 0) *dt = s[0];
}

// ---------------- feat = normalize(embedding[iid]) ----------------
__global__ void k_feat0(const float* __restrict__ emb, const int* __restrict__ iid,
                        float* __restrict__ feat) {
    int row = blockIdx.x * 4 + (threadIdx.x >> 6);
    int l = threadIdx.x & 63;
    const float* p = emb + (long long)iid[row] * D_;
    float a = p[l], b = p[l + 64];
    float ss = wsum(a * a + b * b);
    float s = 1.f / (sqrtf(ss) + 1e-12f);
    float* q = feat + (long long)row * D_;
    q[l] = a * s; q[l + 64] = b * s;
}

// ---------------- stage-A per-graph weighted aggregation (edges of graph g are [50g,50g+50)) ----
__global__ void k_aggA_g(const int* __restrict__ esrc, const int* __restrict__ edst,
                         const float* __restrict__ ew, const float* __restrict__ feat,
                         float* __restrict__ m_in, float* __restrict__ m_out) {
    __shared__ float sfeat[P_ * D_];
    __shared__ float smin[P_ * D_];
    __shared__ float smout[P_ * D_];
    __shared__ int ses[P_], sed[P_];
    __shared__ float sw[P_], swin[P_], swout[P_];
    int g = blockIdx.x, t = threadIdx.x;
    int n0 = g * P_;
    long long base = (long long)n0 * D_;
    for (int i = t; i < P_ * D_; i += 256) {
        sfeat[i] = feat[base + i];
        smin[i] = 0.f; smout[i] = 0.f;
    }
    if (t < P_) {
        int E0 = g * P_ + t;
        ses[t] = esrc[E0] - n0;
        sed[t] = edst[E0] - n0;
        sw[t] = ew[E0];
    }
    __syncthreads();
    int d = t & 127;
    // thread t owns column d of smin (t<128) / smout (t>=128): race-free serialization
    for (int e = 0; e < P_; e++) {
        int ls = ses[e], ld = sed[e];
        float w = sw[e];
        if (t < 128) smin[ld * D_ + d] += sfeat[ls * D_ + d] * w;
        else         smout[ls * D_ + d] += sfeat[ld * D_ + d] * w;
    }
    if (t < P_) {
        float wi = 0.f, wo = 0.f;
        for (int e = 0; e < P_; e++) {
            if (sed[e] == t) wi += sw[e];
            if (ses[e] == t) wo += sw[e];
        }
        swin[t] = (wi > 0.f) ? 1.f / wi : 1.f;
        swout[t] = (wo > 0.f) ? 1.f / wo : 1.f;
    }
    __syncthreads();
    for (int i = t; i < P_ * D_; i += 256) {
        int n = i >> 7;
        m_in[base + i] = smin[i] * swin[n];
        m_out[base + i] = smout[i] * swout[n];
    }
}

// ---------------- per-graph GCN aggregation: out = nrm * seg(v*nrm), mask = (t<=tv)&&(s!=d) ----
template<int MUL>
__global__ void k_gagg_g(const int* __restrict__ esrc, const int* __restrict__ edst,
                         const float* __restrict__ et, const float* __restrict__ dtp, float tfac,
                         const float* __restrict__ a, const float* __restrict__ b,
                         float* __restrict__ out) {
    __shared__ float sv[P_ * D_];
    __shared__ float sagg[P_ * D_];
    __shared__ int ses[P_], sed[P_], sml[P_];
    __shared__ float snrm[P_];
    int g = blockIdx.x, t = threadIdx.x;
    int n0 = g * P_;
    long long base = (long long)n0 * D_;
    float tv = tfac * dtp[0];
    if (t < P_) {
        int E0 = g * P_ + t;
        int s = esrc[E0], dd = edst[E0];
        ses[t] = s - n0; sed[t] = dd - n0;
        sml[t] = (s != dd) && (et[E0] <= tv);
    }
    __syncthreads();
    if (t < P_) {
        int deg = 0;
        for (int e = 0; e < P_; e++)
            if (sml[e]) deg += (ses[e] == t) + (sed[e] == t);
        snrm[t] = rsqrtf(fmaxf((float)deg, 1.f));
    }
    __syncthreads();
    for (int i = t; i < P_ * D_; i += 256) {
        int n = i >> 7;
        float v = a[base + i];
        if (MUL) v *= b[base + i];
        sv[i] = v * snrm[n];
        sagg[i] = 0.f;
    }
    __syncthreads();
    if (t < 128) {  // thread t owns column t of sagg: race-free
        int d = t;
        for (int e = 0; e < P_; e++) {
            if (!sml[e]) continue;
            int ls = ses[e], ld = sed[e];
            sagg[ld * D_ + d] += sv[ls * D_ + d];
            sagg[ls * D_ + d] += sv[ld * D_ + d];
        }
    }
    __syncthreads();
    for (int i = t; i < P_ * D_; i += 256) {
        int n = i >> 7;
        out[base + i] = sagg[i] * snrm[n];
    }
}

// M[k][j] = sum_{c<256} W[k][c] * wih[j][coff+c]
__global__ void k_prec(const float* __restrict__ W, const float* __restrict__ wih, int coff,
                       float* __restrict__ M) {
    int idx = blockIdx.x * 256 + threadIdx.x;
    if (idx >= 128 * 384) return;
    int k = idx / 384, j = idx % 384;
    const float* wr = W + (long long)k * 256;
    const float* ir = wih + (long long)j * 512 + coff;
    float s = 0.f;
    for (int c = 0; c < 256; c++) s += wr[c] * ir[c];
    M[(long long)k * 384 + j] = s;
}

// ---------------- MFMA bf16 GEMM: C = act((A1@B1 [+ A2@B2]) + bias1 + bias2) * cscale * outmul
// fp32 in/out, bf16 MFMA internally. BM=BN=128, 4 waves of 64x64. K=128 (256 if DUAL).
// BT=1: B stored [col][128] row-major (B^T). BT=0: B row-major [k][ldb].
template<int DUAL, int BT, int ACT, int SWAPG>
__launch_bounds__(256)
__global__ void k_mm(const float* __restrict__ A1, const float* __restrict__ B1,
                     const float* __restrict__ A2, const float* __restrict__ B2, int ldb,
                     const float* __restrict__ bias1, const float* __restrict__ bias2,
                     const float* __restrict__ cscale, float outmul,
                     float* __restrict__ C, int ncols, long long ldc) {
    __shared__ unsigned short As[128 * 40];  // padded stride 40 elems = 80B
    __shared__ unsigned short Bs[128 * 40];  // Bs[col][k]
    const int t = threadIdx.x;
    const int bm = SWAPG ? blockIdx.x : blockIdx.y;
    const int bn = SWAPG ? blockIdx.y : blockIdx.x;
    const int lane = t & 63, wid = t >> 6;
    const int wr = wid >> 1, wc = wid & 1;
    const int lr = lane & 15, lh = lane >> 4;
    f32x4 acc[4][4] = {};
    constexpr int KTOT = DUAL ? 256 : 128;
    for (int ks = 0; ks < KTOT; ks += 32) {
        #pragma unroll
        for (int i = 0; i < 4; i++) {  // A: 128 rows x 32 k
            int idx = i * 256 + t;
            int row = idx >> 3, kl = (idx & 7) * 4;
            int gk = ks + kl;
            const float* Ap = A1; int ak = gk;
            if (DUAL && gk >= 128) { Ap = A2; ak = gk - 128; }
            float4 v = *(const float4*)&Ap[((long long)bm * 128 + row) * 128 + ak];
            ushort4 bb; bb.x = f2b(v.x); bb.y = f2b(v.y); bb.z = f2b(v.z); bb.w = f2b(v.w);
            *(ushort4*)&As[row * 40 + kl] = bb;
        }
        if (BT) {
            #pragma unroll
            for (int i = 0; i < 4; i++) {
                int idx = i * 256 + t;
                int col = idx >> 3, kl = (idx & 7) * 4;
                int gk = ks + kl;
                long long gcol = (long long)bn * 128 + col;
                float4 v = make_float4(0.f, 0.f, 0.f, 0.f);
                if (gcol < ncols) v = *(const float4*)&B1[gcol * 128 + gk];
                ushort4 bb; bb.x = f2b(v.x); bb.y = f2b(v.y); bb.z = f2b(v.z); bb.w = f2b(v.w);
                *(ushort4*)&Bs[col * 40 + kl] = bb;
            }
        } else {
            #pragma unroll
            for (int i = 0; i < 16; i++) {  // 32k x 128col scalar
                int idx = i * 256 + t;
                int col = idx & 127, kl = idx >> 7;
                int gk = ks + kl;
                const float* Bp = B1; int bk = gk;
                if (DUAL && gk >= 128) { Bp = B2; bk = gk - 128; }
                int gcol = bn * 128 + col;
                float v = (gcol < ncols) ? Bp[(long long)bk * ldb + gcol] : 0.f;
                Bs[col * 40 + kl] = f2b(v);
            }
        }
        __syncthreads();
        bf16x8 af[4], bf[4];
        #pragma unroll
        for (int f = 0; f < 4; f++) {
            u16x8 ar = *(const u16x8*)&As[(wr * 64 + f * 16 + lr) * 40 + lh * 8];
            u16x8 br = *(const u16x8*)&Bs[(wc * 64 + f * 16 + lr) * 40 + lh * 8];
            af[f] = __builtin_bit_cast(bf16x8, ar);
            bf[f] = __builtin_bit_cast(bf16x8, br);
        }
        #pragma unroll
        for (int fr = 0; fr < 4; fr++)
            #pragma unroll
            for (int fc = 0; fc < 4; fc++)
                acc[fr][fc] = __builtin_amdgcn_mfma_f32_16x16x32_bf16(af[fr], bf[fc], acc[fr][fc], 0, 0, 0);
        __syncthreads();
    }
    #pragma unroll
    for (int fc = 0; fc < 4; fc++) {
        int col = bn * 128 + wc * 64 + fc * 16 + lr;
        if (col >= ncols) continue;
        float bb = (bias1 ? bias1[col] : 0.f) + (bias2 ? bias2[col] : 0.f);
        float cs = (cscale ? cscale[col] : 1.f) * outmul;
        #pragma unroll
        for (int fr = 0; fr < 4; fr++) {
            long long row0 = (long long)bm * 128 + wr * 64 + fr * 16 + lh * 4;
            #pragma unroll
            for (int r = 0; r < 4; r++) {
                float v = (acc[fr][fc][r] + bb) * cs;
                if (ACT == 1) v = sig(v);
                else if (ACT == 2) v = tanhf(v);
                C[(row0 + r) * ldc + col] = v;
            }
        }
    }
}

// ---------------- GRU + renorm ----------------
__global__ void k_gru(const float* __restrict__ gi, const float* __restrict__ gh,
                      float* __restrict__ feat) {
    int row = blockIdx.x * 4 + (threadIdx.x >> 6);
    int l = threadIdx.x & 63;
    const float* gir = gi + (long long)row * 384;
    const float* ghr = gh + (long long)row * 384;
    float* fr = feat + (long long)row * 128;
    float nv[2]; float ss = 0.f;
    #pragma unroll
    for (int tq = 0; tq < 2; tq++) {
        int d = l + tq * 64;
        float ir = gir[d], iz = gir[128 + d], in_ = gir[256 + d];
        float hr = ghr[d], hz = ghr[128 + d], hn = ghr[256 + d];
        float r = sig(ir + hr);
        float z = sig(iz + hz);
        float n = tanhf(in_ + r * hn);
        float fv = fr[d];
        nv[tq] = (1.f - z) * n + z * fv;
        ss += nv[tq] * nv[tq];
    }
    ss = wsum(ss);
    float s = 1.f / fmaxf(sqrtf(ss), 1e-12f);
    fr[l] = nv[0] * s; fr[l + 64] = nv[1] * s;
}

// dh = normalize((1-z)*(u-h)); acc += accw*dh; h = feat + hfac*dt*dh
__global__ void k_dhu(const float* __restrict__ z, const float* __restrict__ u,
                      const float* __restrict__ hprev, const float* __restrict__ feat,
                      float* __restrict__ acc, float* __restrict__ h,
                      const float* __restrict__ dtp, float accw, float hfac, int first) {
    int row = blockIdx.x * 4 + (threadIdx.x >> 6);
    int l = threadIdx.x & 63;
    long long bse = (long long)row * 128;
    float v[2]; float ss = 0.f;
    #pragma unroll
    for (int tq = 0; tq < 2; tq++) {
        int d = l + tq * 64;
        float zz = z[bse + d], uu = u[bse + d], hh = hprev[bse + d];
        v[tq] = (1.f - zz) * (uu - hh);
        ss += v[tq] * v[tq];
    }
    ss = wsum(ss);
    float s = 1.f / fmaxf(sqrtf(ss), 1e-12f);
    float dt = dtp[0];
    #pragma unroll
    for (int tq = 0; tq < 2; tq++) {
        int d = l + tq * 64;
        float kv = v[tq] * s;
        float an = (first ? 0.f : acc[bse + d]) + accw * kv;
        acc[bse + d] = an;
        if (hfac != 0.f) h[bse + d] = feat[bse + d] + hfac * dt * kv;
    }
}

__global__ void k_fin(float* __restrict__ feat, const float* __restrict__ acc,
                      const float* __restrict__ dtp) {
    int row = blockIdx.x * 4 + (threadIdx.x >> 6);
    int l = threadIdx.x & 63;
    long long base = (long long)row * 128;
    float dt6 = (*dtp) / 6.f;
    float v0 = feat[base + l] + dt6 * acc[base + l];
    float v1 = feat[base + l + 64] + dt6 * acc[base + l + 64];
    float ss = wsum(v0 * v0 + v1 * v1);
    float s = 1.f / sqrtf(ss);
    feat[base + l] = v0 * s; feat[base + l + 64] = v1 * s;
}

// ---------------- readout ----------------
__global__ void k_fv(const float* __restrict__ feat, const int* __restrict__ last,
                     const float* __restrict__ Wv, const float* __restrict__ bv,
                     float* __restrict__ fv) {
    __shared__ float fr[128];
    int b = blockIdx.x; int j = threadIdx.x;
    fr[j] = feat[(long long)last[b] * 128 + j];
    __syncthreads();
    float s = bv[j];
    for (int k = 0; k < 128; k++) s += fr[k] * Wv[(long long)k * 128 + j];
    fv[(long long)b * 128 + j] = s;
}

__global__ void k_e(const float* __restrict__ fu, const float* __restrict__ fv,
                    const int* __restrict__ gid, const float* __restrict__ fce,
                    float* __restrict__ e) {
    int row = blockIdx.x * 4 + (threadIdx.x >> 6);
    int l = threadIdx.x & 63;
    int g = gid[row];
    float s = 0.f;
    #pragma unroll
    for (int tq = 0; tq < 2; tq++) {
        int d = l + tq * 64;
        float x = fu[(long long)row * 128 + d] + fv[(long long)g * 128 + d];
        s += sig(x) * fce[d];
    }
    s = wsum(s);
    if (l == 0) e[row] = s;
}

__global__ void k_softg(const float* __restrict__ e, float* __restrict__ alpha) {
    int b = blockIdx.x; int l = threadIdx.x;
    float v = (l < P_) ? e[b * P_ + l] : -1e30f;
    float m = wmax(v);
    float ex = (l < P_) ? expf(v - m) : 0.f;
    float s = wsum(ex);
    if (l < P_) alpha[b * P_ + l] = ex / s;
}

__global__ void k_srg(const float* __restrict__ feat, const float* __restrict__ alpha,
                      float* __restrict__ srg) {
    int b = blockIdx.x; int d = threadIdx.x;
    float s = 0.f;
    for (int p = 0; p < P_; p++)
        s += feat[(long long)(b * P_ + p) * 128 + d] * alpha[b * P_ + p];
    srg[(long long)b * 128 + d] = s;
}

__global__ void k_sr(const float* __restrict__ feat, const int* __restrict__ last,
                     const float* __restrict__ srg, const float* __restrict__ Wsr,
                     float* __restrict__ sr) {
    __shared__ float in[256];
    __shared__ float red[2];
    int b = blockIdx.x; int j = threadIdx.x;
    in[j] = feat[(long long)last[b] * 128 + j];
    in[128 + j] = srg[(long long)b * 128 + j];
    __syncthreads();
    float s = 0.f;
    for (int k = 0; k < 256; k++) s += in[k] * Wsr[(long long)k * 128 + j];
    float ss = wsum(s * s);
    if ((j & 63) == 0) red[j >> 6] = ss;
    __syncthreads();
    float nrm = sqrtf(red[0] + red[1]);
    sr[(long long)b * 128 + j] = s / (nrm + 1e-12f);
}

__global__ void k_rn(const float* __restrict__ emb, float* __restrict__ rn) {
    int row = blockIdx.x * 4 + (threadIdx.x >> 6);
    if (row >= V_) return;
    int l = threadIdx.x & 63;
    const float* p = emb + (long long)row * 128;
    float a = p[l], b = p[l + 64];
    float ss = wsum(a * a + b * b);
    if (l == 0) rn[row] = 1.f / (sqrtf(ss) + 1e-12f);
}

__global__ void k_lsm(float* __restrict__ out) {
    __shared__ float sm[256], ssum[256];
    int b = blockIdx.x;
    float* row = out + (long long)b * V_;
    float m = -1e30f, s = 0.f;
    for (int i = threadIdx.x; i < V_; i += 256) {
        float v = row[i];
        if (v > m) { s = s * expf(m - v) + 1.f; m = v; }
        else s += expf(v - m);
    }
    sm[threadIdx.x] = m; ssum[threadIdx.x] = s; __syncthreads();
    for (int o = 128; o; o >>= 1) {
        if (threadIdx.x < o) {
            float m1 = sm[threadIdx.x], s1 = ssum[threadIdx.x];
            float m2 = sm[threadIdx.x + o], s2 = ssum[threadIdx.x + o];
            float mm = fmaxf(m1, m2);
            sm[threadIdx.x] = mm;
            ssum[threadIdx.x] = s1 * expf(m1 - mm) + s2 * expf(m2 - mm);
        }
        __syncthreads();
    }
    float M = sm[0], L = logf(ssum[0]);
    for (int i = threadIdx.x; i < V_; i += 256) row[i] = row[i] - M - L;
}

// ================= host orchestration =================
extern "C" void kernel_launch(void* const* d_in, const int* in_sizes, int n_in,
                              void* d_out, int out_size, void* d_ws, size_t ws_size,
                              hipStream_t stream) {
    const int* iid   = (const int*)d_in[0];
    const int* esrc  = (const int*)d_in[1];
    const int* edst  = (const int*)d_in[2];
    const int* gid   = (const int*)d_in[3];
    const int* last  = (const int*)d_in[4];
    const float* ew  = (const float*)d_in[5];
    const float* et  = (const float*)d_in[6];
    const float* emb = (const float*)d_in[7];
    const float* W1  = (const float*)d_in[8];
    const float* W2  = (const float*)d_in[9];
    const float* wih = (const float*)d_in[10];
    const float* whh = (const float*)d_in[11];
    const float* bih = (const float*)d_in[12];
    const float* bhh = (const float*)d_in[13];
    const float* Wxr = (const float*)d_in[14]; const float* bxr = (const float*)d_in[15];
    const float* Wxz = (const float*)d_in[16]; const float* bxz = (const float*)d_in[17];
    const float* Wxh = (const float*)d_in[18]; const float* bxh = (const float*)d_in[19];
    const float* Whr = (const float*)d_in[20]; const float* bhr = (const float*)d_in[21];
    const float* Whz = (const float*)d_in[22]; const float* bhz = (const float*)d_in[23];
    const float* Whh = (const float*)d_in[24]; const float* bhh2 = (const float*)d_in[25];
    const float* fcu = (const float*)d_in[26];
    const float* fvw = (const float*)d_in[27]; const float* fvbv = (const float*)d_in[28];
    const float* fce = (const float*)d_in[29];
    const float* fsr = (const float*)d_in[30];
    float* out = (float*)d_out;

    float* Wk = (float*)d_ws;
    auto S = [&](int i) { return Wk + (long long)i * NS_; };
    // N x 384 buffers occupy THREE slots (384 = 3*128).
    float* FEAT = S(0);
    float* MIN = S(1);  float* H   = S(1);
    float* MOUT = S(2); float* ACC = S(2);
    float* GI = S(3);                       // [3,6)
    float* GH = S(6);                       // [6,9)
    float* AX = S(3);                       // alive only after GI dead
    float* AH = S(4);
    float* RB = S(5);
    float* ZB = S(6);                       // alive only after GH dead
    float* FU = S(3);
    float* small = Wk + 9 * NS_;
    float* evec = small;   small += N_;
    float* alpha = small;  small += N_;
    float* dtp = small;    small += 64;
    float* M1 = small;     small += 128 * 384;
    float* M2 = small;     small += 128 * 384;
    float* fvb = small;    small += B_ * 128;
    float* srg = small;    small += B_ * 128;
    float* srb = small;    small += B_ * 128;
    float* rnv = small;    small += V_;

    k_dtmax<<<1, 256, 0, stream>>>(et, dtp);
    k_feat0<<<N_ / 4, 256, 0, stream>>>(emb, iid, FEAT);

    // ---- stage A: weighted neighbor agg + GRU ----
    k_aggA_g<<<B_, 256, 0, stream>>>(esrc, edst, ew, FEAT, MIN, MOUT);
    k_prec<<<192, 256, 0, stream>>>(W1, wih, 0, M1);
    k_prec<<<192, 256, 0, stream>>>(W2, wih, 256, M2);
    k_mm<1, 0, 0, 0><<<dim3(3, N_ / 128), 256, 0, stream>>>(
        MIN, M1, MOUT, M2, 384, bih, nullptr, nullptr, 1.f, GI, 384, 384);
    k_mm<0, 1, 0, 0><<<dim3(3, N_ / 128), 256, 0, stream>>>(
        FEAT, whh, nullptr, nullptr, 128, bhh, nullptr, nullptr, 1.f, GH, 384, 384);
    k_gru<<<N_ / 4, 256, 0, stream>>>(GI, GH, FEAT);

    // ---- stage B: RK4 ODE ----
    hipMemcpyAsync(H, FEAT, NS_ * 4, hipMemcpyDeviceToDevice, stream);

    auto fstep = [&](float tfac, bool newmask, bool hx_same,
                     float accw, float hfac, int first) {
        if (newmask)
            k_gagg_g<0><<<B_, 256, 0, stream>>>(esrc, edst, et, dtp, tfac, FEAT, nullptr, AX);
        const float* AHp = AX;
        if (!hx_same) {
            k_gagg_g<0><<<B_, 256, 0, stream>>>(esrc, edst, et, dtp, tfac, H, nullptr, AH);
            AHp = AH;
        }
        k_mm<1, 0, 1, 0><<<dim3(1, N_ / 128), 256, 0, stream>>>(
            AX, Wxr, AHp, Whr, 128, bxr, bhr, nullptr, 1.f, RB, 128, 128);
        k_mm<1, 0, 1, 0><<<dim3(1, N_ / 128), 256, 0, stream>>>(
            AX, Wxz, AHp, Whz, 128, bxz, bhz, nullptr, 1.f, ZB, 128, 128);
        k_gagg_g<1><<<B_, 256, 0, stream>>>(esrc, edst, et, dtp, tfac, RB, H, AH);
        k_mm<1, 0, 2, 0><<<dim3(1, N_ / 128), 256, 0, stream>>>(
            AX, Wxh, AH, Whh, 128, bxh, bhh2, nullptr, 1.f, RB, 128, 128);
        k_dhu<<<N_ / 4, 256, 0, stream>>>(ZB, RB, H, FEAT, ACC, H, dtp, accw, hfac, first);
    };

    fstep(0.0f, true, true, 1.f, 0.5f, 1);
    fstep(0.5f, true, false, 2.f, 0.5f, 0);
    fstep(0.5f, false, false, 2.f, 1.0f, 0);
    fstep(1.0f, true, false, 1.f, 0.0f, 0);
    k_fin<<<N_ / 4, 256, 0, stream>>>(FEAT, ACC, dtp);

    // ---- readout ----
    k_mm<0, 0, 0, 0><<<dim3(1, N_ / 128), 256, 0, stream>>>(
        FEAT, fcu, nullptr, nullptr, 128, nullptr, nullptr, nullptr, 1.f, FU, 128, 128);
    k_fv<<<B_, 128, 0, stream>>>(FEAT, last, fvw, fvbv, fvb);
    k_e<<<N_ / 4, 256, 0, stream>>>(FU, fvb, gid, fce, evec);
    k_softg<<<B_, 64, 0, stream>>>(evec, alpha);
    k_srg<<<B_, 128, 0, stream>>>(FEAT, alpha, srg);
    k_sr<<<B_, 128, 0, stream>>>(FEAT, last, srg, fsr, srb);
    k_rn<<<(V_ + 3) / 4, 256, 0, stream>>>(emb, rnv);
    k_mm<0, 1, 0, 1><<<dim3(B_ / 128, (V_ + 127) / 128), 256, 0, stream>>>(
        srb, emb, nullptr, nullptr, 128, nullptr, nullptr, rnv, SCALE_, out, V_, V_);
    k_lsm<<<B_, 256, 0, stream>>>(out);
}